// Round 1
// baseline (230.249 us; speedup 1.0000x reference)
//
#include <hip/hip_runtime.h>

typedef __attribute__((ext_vector_type(8))) short short8;
typedef __attribute__((ext_vector_type(4))) float f32x4;

#define PI_F 3.14159265358979323846f

__device__ __forceinline__ unsigned short f2bf(float x) {
  union { float f; unsigned u; } v; v.f = x;
  unsigned r = v.u + 0x7fffu + ((v.u >> 16) & 1u);
  return (unsigned short)(r >> 16);
}

__device__ __forceinline__ void blob4(float x, float* dst) {
#pragma unroll
  for (int k = 0; k < 4; ++k) {
    float c = (k + 0.5f) * 0.25f;
    float t = (x - c) * 4.0f;
    dst[k] = __expf(-0.5f * t * t);
  }
}

// Convert fp32 weights -> bf16 workspace. Layout:
//   wb[l*4096 + n*64 + k] = W_l[n][k]  (l = 0..5)
//   wb[24576 + n*64 + k]  = W6[n][k] for n<3 else 0   (padded 16x64)
__global__ void prep_weights(
    const float* __restrict__ W0, const float* __restrict__ W1,
    const float* __restrict__ W2, const float* __restrict__ W3,
    const float* __restrict__ W4, const float* __restrict__ W5,
    const float* __restrict__ W6, unsigned short* __restrict__ wb)
{
  int idx = blockIdx.x * blockDim.x + threadIdx.x;
  if (idx < 24576) {
    int l = idx >> 12;
    const float* W = (l==0)?W0:(l==1)?W1:(l==2)?W2:(l==3)?W3:(l==4)?W4:W5;
    wb[idx] = f2bf(W[idx & 4095]);
  } else if (idx < 25600) {
    int j = idx - 24576;
    wb[idx] = (j < 192) ? f2bf(W6[j]) : (unsigned short)0;
  }
}

// One wave = 64 batch rows, fully wave-autonomous.
// LDS X tile holds activations as [row][feature] bf16, stride 72 (144 B, 16B-aligned).
// Layer l computes H^T = W_l * X^T via mfma_f32_16x16x32_bf16:
//   A-frag = W rows  (m = lane&15 -> neuron-in-tile, k = quad*8+j)
//   B-frag = X rows  (n = lane&15 -> batch-in-group, k = quad*8+j)
//   C/D: col = lane&15 = batch, row = quad*4+reg = neuron  -> 4 consecutive
//   neurons per lane -> packed ds_write_b64 back into X (in-place, row-disjoint).
__global__ __launch_bounds__(256, 3) void nrc_mlp(
    const float* __restrict__ P, const float* __restrict__ WI,
    const float* __restrict__ NRM, const float* __restrict__ ALPHA,
    const float* __restrict__ BETA, const float* __restrict__ R,
    const unsigned short* __restrict__ wb, float* __restrict__ out)
{
  __shared__ __align__(16) unsigned short xlds[4][64][72];  // 36864 B
  __shared__ __align__(16) float resf[4][64][4];            //  4096 B
  const int lane = threadIdx.x & 63;
  const int wv   = threadIdx.x >> 6;
  unsigned short (* __restrict__ X)[72] = xlds[wv];
  float (* __restrict__ RES)[4] = resf[wv];
  const int n15 = lane & 15;
  const int q   = lane >> 4;
  const int chunk = blockIdx.x * 4 + wv;     // 4096 blocks * 4 waves = 16384 chunks
  const int row0 = chunk * 64;

  // ---------------- encoding: lane <-> row ----------------
  {
    const int row = row0 + lane;
    float f[64];
    float pv[3];
    pv[0] = P[row*3+0]; pv[1] = P[row*3+1]; pv[2] = P[row*3+2];
#pragma unroll
    for (int d = 0; d < 3; ++d) {
      float a = pv[d] * PI_F;
#pragma unroll
      for (int i = 0; i < 6; ++i) {
        float ai = a * (float)(1 << i);
        f[d*12 + i]     = __sinf(ai);
        f[d*12 + 6 + i] = __cosf(ai);
      }
    }
    {
      float wx = WI[row*3+0], wy = WI[row*3+1], wz = WI[row*3+2];
      float th = acosf(fminf(1.f, fmaxf(-1.f, wz))) * (1.0f/PI_F);
      float ph = atan2f(wy, wx) * (1.0f/(2.0f*PI_F)) + 0.5f;
      blob4(th, &f[36]);
      blob4(ph, &f[40]);
    }
    {
      float nx = NRM[row*3+0], ny = NRM[row*3+1], nz = NRM[row*3+2];
      float th = acosf(fminf(1.f, fmaxf(-1.f, nz))) * (1.0f/PI_F);
      float ph = atan2f(ny, nx) * (1.0f/(2.0f*PI_F)) + 0.5f;
      blob4(th, &f[44]);
      blob4(ph, &f[48]);
    }
    blob4(1.0f - __expf(-R[row]), &f[52]);
    f[56] = ALPHA[row*3+0]; f[57] = ALPHA[row*3+1]; f[58] = ALPHA[row*3+2];
    f[59] = BETA[row*3+0];  f[60] = BETA[row*3+1];  f[61] = BETA[row*3+2];
    f[62] = 1.0f; f[63] = 1.0f;
#pragma unroll
    for (int g8 = 0; g8 < 8; ++g8) {
      short8 v;
#pragma unroll
      for (int j = 0; j < 8; ++j) v[j] = (short)f2bf(f[g8*8 + j]);
      *(short8*)(&X[lane][g8*8]) = v;
    }
  }
  __syncthreads();

  // ---------------- 6 hidden layers ----------------
  for (int l = 0; l < 6; ++l) {
    const unsigned short* W = wb + l*4096;
    short8 af[4][2];
#pragma unroll
    for (int t = 0; t < 4; ++t) {
      af[t][0] = *(const short8*)(W + (t*16 + n15)*64 + q*8);
      af[t][1] = *(const short8*)(W + (t*16 + n15)*64 + 32 + q*8);
    }
#pragma unroll
    for (int g = 0; g < 4; ++g) {
      const int xr = g*16 + n15;
      short8 b0 = *(const short8*)(&X[xr][q*8]);
      short8 b1 = *(const short8*)(&X[xr][32 + q*8]);
      f32x4 acc[4];
#pragma unroll
      for (int t = 0; t < 4; ++t) {
        f32x4 c = {0.f, 0.f, 0.f, 0.f};
        c = __builtin_amdgcn_mfma_f32_16x16x32_bf16(af[t][0], b0, c, 0, 0, 0);
        c = __builtin_amdgcn_mfma_f32_16x16x32_bf16(af[t][1], b1, c, 0, 0, 0);
        acc[t] = c;
      }
#pragma unroll
      for (int t = 0; t < 4; ++t) {
        unsigned h0 = f2bf(fmaxf(acc[t][0], 0.f));
        unsigned h1 = f2bf(fmaxf(acc[t][1], 0.f));
        unsigned h2 = f2bf(fmaxf(acc[t][2], 0.f));
        unsigned h3 = f2bf(fmaxf(acc[t][3], 0.f));
        uint2 pk;
        pk.x = h0 | (h1 << 16);
        pk.y = h2 | (h3 << 16);
        *(uint2*)(&X[xr][t*16 + q*4]) = pk;   // neurons t*16+q*4 .. +3
      }
    }
    __syncthreads();
  }

  // ---------------- output layer (3x64, padded to 16x64) ----------------
  {
    const unsigned short* W6b = wb + 24576;
    short8 a0 = *(const short8*)(W6b + n15*64 + q*8);
    short8 a1 = *(const short8*)(W6b + n15*64 + 32 + q*8);
#pragma unroll
    for (int g = 0; g < 4; ++g) {
      const int xr = g*16 + n15;
      short8 b0 = *(const short8*)(&X[xr][q*8]);
      short8 b1 = *(const short8*)(&X[xr][32 + q*8]);
      f32x4 c = {0.f, 0.f, 0.f, 0.f};
      c = __builtin_amdgcn_mfma_f32_16x16x32_bf16(a0, b0, c, 0, 0, 0);
      c = __builtin_amdgcn_mfma_f32_16x16x32_bf16(a1, b1, c, 0, 0, 0);
      if (q == 0) {          // rows 0..3 of C = output neurons; j<3 valid
        float* rp = RES[xr];
        rp[0] = c[0]; rp[1] = c[1]; rp[2] = c[2];
      }
    }
  }
  __syncthreads();

  // ---------------- (alpha+beta) scale + coalesced store ----------------
#pragma unroll
  for (int rep = 0; rep < 3; ++rep) {
    int dd = rep*64 + lane;          // 0..191 within this wave's chunk
    int ri = dd / 3;
    int j  = dd - ri*3;
    float v = RES[ri][j];
    int gidx = row0*3 + dd;
    out[gidx] = v * (ALPHA[gidx] + BETA[gidx]);
  }
}

extern "C" void kernel_launch(void* const* d_in, const int* in_sizes, int n_in,
                              void* d_out, int out_size, void* d_ws, size_t ws_size,
                              hipStream_t stream) {
  const float* P  = (const float*)d_in[0];
  const float* WI = (const float*)d_in[1];
  const float* NR = (const float*)d_in[2];
  const float* AL = (const float*)d_in[3];
  const float* BE = (const float*)d_in[4];
  const float* R  = (const float*)d_in[5];
  const float* W0 = (const float*)d_in[6];
  const float* W1 = (const float*)d_in[7];
  const float* W2 = (const float*)d_in[8];
  const float* W3 = (const float*)d_in[9];
  const float* W4 = (const float*)d_in[10];
  const float* W5 = (const float*)d_in[11];
  const float* W6 = (const float*)d_in[12];
  unsigned short* wb = (unsigned short*)d_ws;   // 25600 bf16 = 51200 B
  float* out = (float*)d_out;

  prep_weights<<<100, 256, 0, stream>>>(W0, W1, W2, W3, W4, W5, W6, wb);
  nrc_mlp<<<4096, 256, 0, stream>>>(P, WI, NR, AL, BE, R, wb, out);
}

// Round 2
// 206.949 us; speedup vs baseline: 1.1126x; 1.1126x over previous
//
#include <hip/hip_runtime.h>
#include <hip/hip_bf16.h>

typedef __attribute__((ext_vector_type(8))) short short8;
typedef __attribute__((ext_vector_type(4))) float f32x4;

#define PI_F 3.14159265358979323846f

__device__ __forceinline__ unsigned short f2bf(float x) {
  union { float f; unsigned u; } v; v.f = x;
  unsigned r = v.u + 0x7fffu + ((v.u >> 16) & 1u);
  return (unsigned short)(r >> 16);
}

// pack 2 f32 -> bf16x2 (RNE); lowers to v_cvt_pk_bf16_f32 on gfx950
__device__ __forceinline__ unsigned pk2(float a, float b) {
  __hip_bfloat162 h = __float22bfloat162_rn(make_float2(a, b));
  union { __hip_bfloat162 v; unsigned u; } c; c.v = h; return c.u;
}

__device__ __forceinline__ short8 u2s8(uint4 u) {
  union { uint4 a; short8 b; } c; c.a = u; return c.b;
}

__device__ __forceinline__ void blob4(float x, float* dst) {
#pragma unroll
  for (int k = 0; k < 4; ++k) {
    float c = (k + 0.5f) * 0.25f;
    float t = (x - c) * 4.0f;
    dst[k] = __expf(-0.5f * t * t);
  }
}

// bf16 weights in d_ws. Hidden layers: rows PERMUTED by sigma so that the
// MFMA C-layout (physical row p = t*16 + q*4 + r at lane q) lands logical
// neuron sigma(p) = 32*(t>>1) + 8*q + 4*(t&1) + r exactly into the k-slot
// the next layer's B-fragment expects. W6 stays natural (16x64 zero-pad).
__global__ void prep_weights(
    const float* __restrict__ W0, const float* __restrict__ W1,
    const float* __restrict__ W2, const float* __restrict__ W3,
    const float* __restrict__ W4, const float* __restrict__ W5,
    const float* __restrict__ W6, unsigned short* __restrict__ wb)
{
  int idx = blockIdx.x * blockDim.x + threadIdx.x;
  if (idx < 24576) {
    int l = idx >> 12;
    const float* W = (l==0)?W0:(l==1)?W1:(l==2)?W2:(l==3)?W3:(l==4)?W4:W5;
    int p = (idx >> 6) & 63;
    int k = idx & 63;
    int t = p >> 4, q = (p >> 2) & 3, r = p & 3;
    int src = 32*(t>>1) + 8*q + 4*(t&1) + r;
    wb[idx] = f2bf(W[src*64 + k]);
  } else if (idx < 25600) {
    int j = idx - 24576;
    wb[idx] = (j < 192) ? f2bf(W6[j]) : (unsigned short)0;
  }
}

// One wave = 64 batch rows. LDS used only for (a) encoding transpose,
// (b) epilogue redistribution. All 6 hidden layers run register-resident:
// ReLU + v_cvt_pk_bf16_f32 on the accumulators produces the next layer's
// B-fragments directly (thanks to the sigma row permutation of W).
__global__ __launch_bounds__(256, 4) void nrc_mlp(
    const float* __restrict__ P, const float* __restrict__ WI,
    const float* __restrict__ NRM, const float* __restrict__ ALPHA,
    const float* __restrict__ BETA, const float* __restrict__ R,
    const unsigned short* __restrict__ wb, float* __restrict__ out)
{
  __shared__ __align__(16) unsigned short xlds[4][64][72];  // 36864 B
  __shared__ __align__(16) float resf[4][64][4];            //  4096 B
  const int lane = threadIdx.x & 63;
  const int wv   = threadIdx.x >> 6;
  unsigned short (* __restrict__ X)[72] = xlds[wv];
  float (* __restrict__ RES)[4] = resf[wv];
  const int n15 = lane & 15;
  const int q   = lane >> 4;
  const int row0 = (blockIdx.x * 4 + wv) * 64;   // 4096 blocks * 4 waves

  // ---------------- encoding: lane <-> row ----------------
  {
    const int row = row0 + lane;
    float f[64];
    float pv[3];
    pv[0] = P[row*3+0]; pv[1] = P[row*3+1]; pv[2] = P[row*3+2];
#pragma unroll
    for (int d = 0; d < 3; ++d) {
      float rev = 0.5f * pv[d];          // angle/2pi for freq 2^0 * pi
#pragma unroll
      for (int i = 0; i < 6; ++i) {
        float fr = __builtin_amdgcn_fractf(rev);
        f[d*12 + i]     = __builtin_amdgcn_sinf(fr);
        f[d*12 + 6 + i] = __builtin_amdgcn_cosf(fr);
        rev = rev + rev;
      }
    }
    {
      float wx = WI[row*3+0], wy = WI[row*3+1], wz = WI[row*3+2];
      float th = acosf(fminf(1.f, fmaxf(-1.f, wz))) * (1.0f/PI_F);
      float ph = atan2f(wy, wx) * (1.0f/(2.0f*PI_F)) + 0.5f;
      blob4(th, &f[36]);
      blob4(ph, &f[40]);
    }
    {
      float nx = NRM[row*3+0], ny = NRM[row*3+1], nz = NRM[row*3+2];
      float th = acosf(fminf(1.f, fmaxf(-1.f, nz))) * (1.0f/PI_F);
      float ph = atan2f(ny, nx) * (1.0f/(2.0f*PI_F)) + 0.5f;
      blob4(th, &f[44]);
      blob4(ph, &f[48]);
    }
    blob4(1.0f - __expf(-R[row]), &f[52]);
    f[56] = ALPHA[row*3+0]; f[57] = ALPHA[row*3+1]; f[58] = ALPHA[row*3+2];
    f[59] = BETA[row*3+0];  f[60] = BETA[row*3+1];  f[61] = BETA[row*3+2];
    f[62] = 1.0f; f[63] = 1.0f;
#pragma unroll
    for (int g8 = 0; g8 < 8; ++g8) {
      uint4 v;
      v.x = pk2(f[g8*8+0], f[g8*8+1]);
      v.y = pk2(f[g8*8+2], f[g8*8+3]);
      v.z = pk2(f[g8*8+4], f[g8*8+5]);
      v.w = pk2(f[g8*8+6], f[g8*8+7]);
      *(uint4*)(&X[lane][g8*8]) = v;
    }
  }
  __syncthreads();

  // ---------------- load initial B-fragments (4 groups of 16 rows) -------
  uint4 b0[4], b1[4];
#pragma unroll
  for (int g = 0; g < 4; ++g) {
    b0[g] = *(const uint4*)(&X[g*16 + n15][q*8]);
    b1[g] = *(const uint4*)(&X[g*16 + n15][32 + q*8]);
  }

  // ---------------- 6 hidden layers, fully register-resident -------------
  for (int l = 0; l < 6; ++l) {
    const unsigned short* W = wb + l*4096;
    short8 a0[4], a1[4];
#pragma unroll
    for (int t = 0; t < 4; ++t) {
      a0[t] = *(const short8*)(W + (t*16 + n15)*64 + q*8);
      a1[t] = *(const short8*)(W + (t*16 + n15)*64 + 32 + q*8);
    }
#pragma unroll
    for (int g = 0; g < 4; ++g) {
      short8 bb0 = u2s8(b0[g]);
      short8 bb1 = u2s8(b1[g]);
      f32x4 acc[4];
#pragma unroll
      for (int t = 0; t < 4; ++t) {
        f32x4 c = {0.f, 0.f, 0.f, 0.f};
        c = __builtin_amdgcn_mfma_f32_16x16x32_bf16(a0[t], bb0, c, 0, 0, 0);
        c = __builtin_amdgcn_mfma_f32_16x16x32_bf16(a1[t], bb1, c, 0, 0, 0);
        acc[t] = c;
      }
      // ReLU + pack: these ARE the next layer's fragments (sigma permutation)
      uint4 n0, n1;
      n0.x = pk2(fmaxf(acc[0][0],0.f), fmaxf(acc[0][1],0.f));
      n0.y = pk2(fmaxf(acc[0][2],0.f), fmaxf(acc[0][3],0.f));
      n0.z = pk2(fmaxf(acc[1][0],0.f), fmaxf(acc[1][1],0.f));
      n0.w = pk2(fmaxf(acc[1][2],0.f), fmaxf(acc[1][3],0.f));
      n1.x = pk2(fmaxf(acc[2][0],0.f), fmaxf(acc[2][1],0.f));
      n1.y = pk2(fmaxf(acc[2][2],0.f), fmaxf(acc[2][3],0.f));
      n1.z = pk2(fmaxf(acc[3][0],0.f), fmaxf(acc[3][1],0.f));
      n1.w = pk2(fmaxf(acc[3][2],0.f), fmaxf(acc[3][3],0.f));
      b0[g] = n0; b1[g] = n1;
    }
  }

  // ---------------- output layer (3x64 padded to 16x64) ------------------
  {
    const unsigned short* W6b = wb + 24576;
    short8 a0 = *(const short8*)(W6b + n15*64 + q*8);
    short8 a1 = *(const short8*)(W6b + n15*64 + 32 + q*8);
#pragma unroll
    for (int g = 0; g < 4; ++g) {
      f32x4 c = {0.f, 0.f, 0.f, 0.f};
      c = __builtin_amdgcn_mfma_f32_16x16x32_bf16(a0, u2s8(b0[g]), c, 0, 0, 0);
      c = __builtin_amdgcn_mfma_f32_16x16x32_bf16(a1, u2s8(b1[g]), c, 0, 0, 0);
      if (q == 0) {   // C rows 0..3 = output neurons (0..2 valid)
        *(float4*)(&RES[g*16 + n15][0]) = make_float4(c[0], c[1], c[2], 0.f);
      }
    }
  }
  __syncthreads();

  // ---------------- (alpha+beta) scale + coalesced store ------------------
#pragma unroll
  for (int rep = 0; rep < 3; ++rep) {
    int dd = rep*64 + lane;
    int ri = dd / 3;
    int j  = dd - ri*3;
    float v = RES[ri][j];
    int gidx = row0*3 + dd;
    out[gidx] = v * (ALPHA[gidx] + BETA[gidx]);
  }
}

extern "C" void kernel_launch(void* const* d_in, const int* in_sizes, int n_in,
                              void* d_out, int out_size, void* d_ws, size_t ws_size,
                              hipStream_t stream) {
  const float* P  = (const float*)d_in[0];
  const float* WI = (const float*)d_in[1];
  const float* NR = (const float*)d_in[2];
  const float* AL = (const float*)d_in[3];
  const float* BE = (const float*)d_in[4];
  const float* R  = (const float*)d_in[5];
  const float* W0 = (const float*)d_in[6];
  const float* W1 = (const float*)d_in[7];
  const float* W2 = (const float*)d_in[8];
  const float* W3 = (const float*)d_in[9];
  const float* W4 = (const float*)d_in[10];
  const float* W5 = (const float*)d_in[11];
  const float* W6 = (const float*)d_in[12];
  unsigned short* wb = (unsigned short*)d_ws;   // 25600 bf16 = 51200 B
  float* out = (float*)d_out;

  prep_weights<<<100, 256, 0, stream>>>(W0, W1, W2, W3, W4, W5, W6, wb);
  nrc_mlp<<<4096, 256, 0, stream>>>(P, WI, NR, AL, BE, R, wb, out);
}

// Round 3
// 206.037 us; speedup vs baseline: 1.1175x; 1.0044x over previous
//
#include <hip/hip_runtime.h>

typedef __attribute__((ext_vector_type(8))) short short8;
typedef __attribute__((ext_vector_type(4))) float f32x4;

#define PI_F 3.14159265358979323846f

__device__ __forceinline__ unsigned short f2bf(float x) {  // RNE (prep only)
  union { float f; unsigned u; } v; v.f = x;
  unsigned r = v.u + 0x7fffu + ((v.u >> 16) & 1u);
  return (unsigned short)(r >> 16);
}

// pack 2 f32 -> bf16x2, round-half-up: 2 v_add + 1 v_perm. a -> low half.
__device__ __forceinline__ unsigned pkf(float a, float b) {
  union { float f; unsigned u; } x, y; x.f = a; y.f = b;
  return __builtin_amdgcn_perm(y.u + 0x8000u, x.u + 0x8000u, 0x07060302u);
}

__device__ __forceinline__ short8 u2s8(uint4 u) {
  union { uint4 a; short8 b; } c; c.a = u; return c.b;
}

// acos(z)/pi, z clipped to [-1,1].  ~10 VALU.
__device__ __forceinline__ float acos01(float z) {
  float ax = fminf(fabsf(z), 1.0f);
  float t  = __builtin_amdgcn_sqrtf(1.0f - ax);
  float p  = fmaf(ax, fmaf(ax, fmaf(ax, -0.00596110f, 0.02363618f),
                           -0.06751692f), 0.49998766f);
  p *= t;
  return z >= 0.0f ? p : 1.0f - p;
}

// atan2(y,x)/(2pi) + 0.5  in [0,1].  ~16 VALU.
__device__ __forceinline__ float atan2_01(float y, float x) {
  float ax = fabsf(x), ay = fabsf(y);
  float hi = fmaxf(ax, ay), lo = fminf(ax, ay);
  float r  = lo * __builtin_amdgcn_rcpf(fmaxf(hi, 1e-30f));
  float r2 = r * r;
  float p  = fmaf(r2, fmaf(r2, fmaf(r2, fmaf(r2, fmaf(r2,
               -0.0018655370f, 0.0083800422f), -0.018531250f),
                0.030803547f), -0.052940457f), 0.159151323f);
  float q  = r * p;                       // atan(lo/hi) in turns
  q = (ay > ax) ? 0.25f - q : q;
  q = (x < 0.0f) ? 0.5f - q : q;
  return 0.5f + ((y >= 0.0f) ? q : -q);
}

// gaussian one-blob, 4 bins -> two packed dwords
__device__ __forceinline__ uint2 blob4pk(float x) {
  float x4 = x * 4.0f;
  float e0, e1, e2, e3;
  { float t = x4 - 0.5f; e0 = __builtin_amdgcn_exp2f(t * t * -0.72134752f); }
  { float t = x4 - 1.5f; e1 = __builtin_amdgcn_exp2f(t * t * -0.72134752f); }
  { float t = x4 - 2.5f; e2 = __builtin_amdgcn_exp2f(t * t * -0.72134752f); }
  { float t = x4 - 3.5f; e3 = __builtin_amdgcn_exp2f(t * t * -0.72134752f); }
  return make_uint2(pkf(e0, e1), pkf(e2, e3));
}

// bf16 weights in d_ws. Hidden rows permuted by sigma so MFMA C-layout
// feeds the next layer's B-fragment slots directly (verified R2).
__global__ void prep_weights(
    const float* __restrict__ W0, const float* __restrict__ W1,
    const float* __restrict__ W2, const float* __restrict__ W3,
    const float* __restrict__ W4, const float* __restrict__ W5,
    const float* __restrict__ W6, unsigned short* __restrict__ wb)
{
  int idx = blockIdx.x * blockDim.x + threadIdx.x;
  if (idx < 24576) {
    int l = idx >> 12;
    const float* W = (l==0)?W0:(l==1)?W1:(l==2)?W2:(l==3)?W3:(l==4)?W4:W5;
    int p = (idx >> 6) & 63;
    int k = idx & 63;
    int t = p >> 4, q = (p >> 2) & 3, r = p & 3;
    int src = 32*(t>>1) + 8*q + 4*(t&1) + r;
    wb[idx] = f2bf(W[src*64 + k]);
  } else if (idx < 25600) {
    int j = idx - 24576;
    wb[idx] = (j < 192) ? f2bf(W6[j]) : (unsigned short)0;
  }
}

__global__ __launch_bounds__(256, 4) void nrc_mlp(
    const float* __restrict__ P, const float* __restrict__ WI,
    const float* __restrict__ NRM, const float* __restrict__ ALPHA,
    const float* __restrict__ BETA, const float* __restrict__ R,
    const unsigned short* __restrict__ wb, float* __restrict__ out)
{
  __shared__ __align__(16) unsigned short xlds[4][64][72];  // 36864 B
  const int lane = threadIdx.x & 63;
  const int wv   = threadIdx.x >> 6;
  unsigned short (* __restrict__ X)[72] = xlds[wv];
  float (* __restrict__ RES)[4] = (float (*)[4])(&xlds[wv][0][0]); // alias, safe by dataflow
  const int n15 = lane & 15;
  const int q   = lane >> 4;
  const int row0 = (blockIdx.x * 4 + wv) * 64;

  // ---------------- encoding: lane <-> row, incremental pack ----------------
  {
    const int row = row0 + lane;
    unsigned short* xr = &X[lane][0];

    // dim 0 -> features 0..11
    float s0[6], c0[6], s1[6], c1[6], s2[6], c2[6];
    {
      float rev = 0.5f * P[row*3+0];
#pragma unroll
      for (int i = 0; i < 6; ++i) {
        float fr = __builtin_amdgcn_fractf(rev);
        s0[i] = __builtin_amdgcn_sinf(fr);
        c0[i] = __builtin_amdgcn_cosf(fr);
        rev = rev + rev;
      }
      rev = 0.5f * P[row*3+1];
#pragma unroll
      for (int i = 0; i < 6; ++i) {
        float fr = __builtin_amdgcn_fractf(rev);
        s1[i] = __builtin_amdgcn_sinf(fr);
        c1[i] = __builtin_amdgcn_cosf(fr);
        rev = rev + rev;
      }
      rev = 0.5f * P[row*3+2];
#pragma unroll
      for (int i = 0; i < 6; ++i) {
        float fr = __builtin_amdgcn_fractf(rev);
        s2[i] = __builtin_amdgcn_sinf(fr);
        c2[i] = __builtin_amdgcn_cosf(fr);
        rev = rev + rev;
      }
    }
    // chunks 0..3: features 0..31 (dims 0,1 and dim2 sin + c2[0..1])
    *(uint4*)(xr +  0) = make_uint4(pkf(s0[0],s0[1]), pkf(s0[2],s0[3]),
                                    pkf(s0[4],s0[5]), pkf(c0[0],c0[1]));
    *(uint4*)(xr +  8) = make_uint4(pkf(c0[2],c0[3]), pkf(c0[4],c0[5]),
                                    pkf(s1[0],s1[1]), pkf(s1[2],s1[3]));
    *(uint4*)(xr + 16) = make_uint4(pkf(s1[4],s1[5]), pkf(c1[0],c1[1]),
                                    pkf(c1[2],c1[3]), pkf(c1[4],c1[5]));
    *(uint4*)(xr + 24) = make_uint4(pkf(s2[0],s2[1]), pkf(s2[2],s2[3]),
                                    pkf(s2[4],s2[5]), pkf(c2[0],c2[1]));

    // spherical blobs
    uint2 bth_wi, bph_wi, bth_n, bph_n, br;
    {
      float wx = WI[row*3+0], wy = WI[row*3+1], wz = WI[row*3+2];
      bth_wi = blob4pk(acos01(wz));
      bph_wi = blob4pk(atan2_01(wy, wx));
    }
    {
      float nx = NRM[row*3+0], ny = NRM[row*3+1], nz = NRM[row*3+2];
      bth_n = blob4pk(acos01(nz));
      bph_n = blob4pk(atan2_01(ny, nx));
    }
    br = blob4pk(1.0f - __builtin_amdgcn_exp2f(R[row] * -1.44269504f));

    // chunk 4: c2[2..5] + th_wi ; chunk 5: ph_wi + th_n ; chunk 6: ph_n + r
    *(uint4*)(xr + 32) = make_uint4(pkf(c2[2],c2[3]), pkf(c2[4],c2[5]),
                                    bth_wi.x, bth_wi.y);
    *(uint4*)(xr + 40) = make_uint4(bph_wi.x, bph_wi.y, bth_n.x, bth_n.y);
    *(uint4*)(xr + 48) = make_uint4(bph_n.x, bph_n.y, br.x, br.y);

    // chunk 7: alpha(3) beta(3) ones(2)
    float a0 = ALPHA[row*3+0], a1 = ALPHA[row*3+1], a2 = ALPHA[row*3+2];
    float e0 = BETA[row*3+0],  e1 = BETA[row*3+1],  e2 = BETA[row*3+2];
    *(uint4*)(xr + 56) = make_uint4(pkf(a0,a1), pkf(a2,e0), pkf(e1,e2),
                                    0x3F803F80u);
  }
  __syncthreads();

  // ---------------- initial B-fragments ----------------
  uint4 b0[4], b1[4];
#pragma unroll
  for (int g = 0; g < 4; ++g) {
    b0[g] = *(const uint4*)(&X[g*16 + n15][q*8]);
    b1[g] = *(const uint4*)(&X[g*16 + n15][32 + q*8]);
  }

  // ---------------- 6 hidden layers, register-resident ----------------
#pragma unroll
  for (int l = 0; l < 6; ++l) {
    const unsigned short* W = wb + l*4096;
    short8 a0[4], a1[4];
#pragma unroll
    for (int t = 0; t < 4; ++t) {
      a0[t] = *(const short8*)(W + (t*16 + n15)*64 + q*8);
      a1[t] = *(const short8*)(W + (t*16 + n15)*64 + 32 + q*8);
    }
#pragma unroll
    for (int g = 0; g < 4; ++g) {
      short8 bb0 = u2s8(b0[g]);
      short8 bb1 = u2s8(b1[g]);
      f32x4 acc[4];
#pragma unroll
      for (int t = 0; t < 4; ++t) {
        f32x4 c = {0.f, 0.f, 0.f, 0.f};
        c = __builtin_amdgcn_mfma_f32_16x16x32_bf16(a0[t], bb0, c, 0, 0, 0);
        c = __builtin_amdgcn_mfma_f32_16x16x32_bf16(a1[t], bb1, c, 0, 0, 0);
        acc[t] = c;
      }
      uint4 n0, n1;
      n0.x = pkf(fmaxf(acc[0][0],0.f), fmaxf(acc[0][1],0.f));
      n0.y = pkf(fmaxf(acc[0][2],0.f), fmaxf(acc[0][3],0.f));
      n0.z = pkf(fmaxf(acc[1][0],0.f), fmaxf(acc[1][1],0.f));
      n0.w = pkf(fmaxf(acc[1][2],0.f), fmaxf(acc[1][3],0.f));
      n1.x = pkf(fmaxf(acc[2][0],0.f), fmaxf(acc[2][1],0.f));
      n1.y = pkf(fmaxf(acc[2][2],0.f), fmaxf(acc[2][3],0.f));
      n1.z = pkf(fmaxf(acc[3][0],0.f), fmaxf(acc[3][1],0.f));
      n1.w = pkf(fmaxf(acc[3][2],0.f), fmaxf(acc[3][3],0.f));
      b0[g] = n0; b1[g] = n1;
    }
  }

  // ---------------- output layer (3x64 padded to 16x64) ----------------
  {
    const unsigned short* W6b = wb + 24576;
    short8 a0 = *(const short8*)(W6b + n15*64 + q*8);
    short8 a1 = *(const short8*)(W6b + n15*64 + 32 + q*8);
#pragma unroll
    for (int g = 0; g < 4; ++g) {
      f32x4 c = {0.f, 0.f, 0.f, 0.f};
      c = __builtin_amdgcn_mfma_f32_16x16x32_bf16(a0, u2s8(b0[g]), c, 0, 0, 0);
      c = __builtin_amdgcn_mfma_f32_16x16x32_bf16(a1, u2s8(b1[g]), c, 0, 0, 0);
      if (q == 0) {
        *(float4*)(&RES[g*16 + n15][0]) = make_float4(c[0], c[1], c[2], 0.f);
      }
    }
  }
  __syncthreads();

  // ---------------- (alpha+beta) scale + coalesced store ----------------
#pragma unroll
  for (int rep = 0; rep < 3; ++rep) {
    int dd = rep*64 + lane;
    int ri = dd / 3;
    int j  = dd - ri*3;
    float v = RES[ri][j];
    int gidx = row0*3 + dd;
    out[gidx] = v * (ALPHA[gidx] + BETA[gidx]);
  }
}

extern "C" void kernel_launch(void* const* d_in, const int* in_sizes, int n_in,
                              void* d_out, int out_size, void* d_ws, size_t ws_size,
                              hipStream_t stream) {
  const float* P  = (const float*)d_in[0];
  const float* WI = (const float*)d_in[1];
  const float* NR = (const float*)d_in[2];
  const float* AL = (const float*)d_in[3];
  const float* BE = (const float*)d_in[4];
  const float* R  = (const float*)d_in[5];
  const float* W0 = (const float*)d_in[6];
  const float* W1 = (const float*)d_in[7];
  const float* W2 = (const float*)d_in[8];
  const float* W3 = (const float*)d_in[9];
  const float* W4 = (const float*)d_in[10];
  const float* W5 = (const float*)d_in[11];
  const float* W6 = (const float*)d_in[12];
  unsigned short* wb = (unsigned short*)d_ws;   // 25600 bf16 = 51200 B
  float* out = (float*)d_out;

  prep_weights<<<100, 256, 0, stream>>>(W0, W1, W2, W3, W4, W5, W6, wb);
  nrc_mlp<<<4096, 256, 0, stream>>>(P, WI, NR, AL, BE, R, wb, out);
}